// Round 14
// baseline (219.618 us; speedup 1.0000x reference)
//
#include <hip/hip_runtime.h>

typedef unsigned short u16;
using bf16x8 = __attribute__((ext_vector_type(8))) __bf16;
using f32x4  = __attribute__((ext_vector_type(4))) float;
using f32x16 = __attribute__((ext_vector_type(16))) float;
using u16x8  = __attribute__((ext_vector_type(8))) unsigned short;
using u16x4  = __attribute__((ext_vector_type(4))) unsigned short;

#define SEQ   2048
#define HID   1024
#define NHEAD 16
#define HD    64
#define BATCH 2
#define NTOK  4096   // BATCH*SEQ

__device__ __forceinline__ u16 f2bf(float f) {
  unsigned u = __builtin_bit_cast(unsigned, f);
  u += 0x7fffu + ((u >> 16) & 1u);
  return (u16)(u >> 16);
}
__device__ __forceinline__ float bf2f(u16 v) {
  unsigned u = ((unsigned)v) << 16;
  return __builtin_bit_cast(float, u);
}

__device__ __forceinline__ void gld_lds16(const void* g, void* l) {
  __builtin_amdgcn_global_load_lds(
      (__attribute__((address_space(1))) void*)(__UINTPTR_TYPE__)g,
      (__attribute__((address_space(3))) void*)l, 16, 0, 0);
}

__device__ __forceinline__ unsigned cvtpk(float lo, float hi) {
  unsigned r;
  asm("v_cvt_pk_bf16_f32 %0, %1, %2" : "=v"(r) : "v"(lo), "v"(hi));
  return r;
}
__device__ __forceinline__ void pswap(unsigned &a, unsigned &b) {
  asm volatile("v_permlane32_swap_b32 %0, %1" : "+v"(a), "+v"(b));
}

// barrier that does NOT drain vmcnt (lane-private global prefetches stay in
// flight); lgkmcnt(0) makes this wave's ds_writes visible before the barrier.
__device__ __forceinline__ void lds_barrier() {
  __builtin_amdgcn_sched_barrier(0);
  asm volatile("s_waitcnt lgkmcnt(0)" ::: "memory");
  __builtin_amdgcn_s_barrier();
  __builtin_amdgcn_sched_barrier(0);
}

// ---------------- fused fp32 -> bf16 convert (X, Wqkv, Wo in one launch) ----
__global__ __launch_bounds__(256) void cvt3_kernel(const float* __restrict__ a, u16* __restrict__ oa,
                                                   const float* __restrict__ b, u16* __restrict__ ob,
                                                   const float* __restrict__ c, u16* __restrict__ oc) {
  const float* in; u16* out; int off;
  int bid = blockIdx.x;
  if (bid < 4096)      { in = a; out = oa; off = bid; }
  else if (bid < 7168) { in = b; out = ob; off = bid - 4096; }
  else                 { in = c; out = oc; off = bid - 7168; }
  int i = (off * 256 + threadIdx.x) * 4;
  float4 v = *reinterpret_cast<const float4*>(in + i);
  u16x4 o = { f2bf(v.x), f2bf(v.y), f2bf(v.z), f2bf(v.w) };
  *reinterpret_cast<u16x4*>(out + i) = o;
}

// ---------------- GEMM: C[M,N] = A[M,K] * B[N,K]^T, 128x128 ----------------
template<bool BF16OUT>
__global__ __launch_bounds__(256) void gemm_bt(const u16* __restrict__ A,
                                               const u16* __restrict__ B,
                                               void* __restrict__ Cv,
                                               int M, int N, int K) {
  __shared__ u16 At[128 * 64];
  __shared__ u16 Bt[128 * 64];
  const int tid  = threadIdx.x;
  const int wave = tid >> 6;
  const int lane = tid & 63;
  const int g    = lane >> 4;
  const int r16  = lane & 15;
  const int wr   = wave >> 1;
  const int wc   = wave & 1;
  const int bm   = blockIdx.y;
  const int bn   = blockIdx.x;

  const u16* Ab = A + (size_t)bm * 128 * K;
  const u16* Bb = B + (size_t)bn * 128 * K;
  const int srow = lane >> 3;
  const int scol = (lane & 7) * 8;

  f32x4 acc[4][4] = {};

  for (int kt = 0; kt < K; kt += 64) {
#pragma unroll
    for (int c = 0; c < 4; ++c) {
      int seg = wave * 4 + c;
      gld_lds16(Ab + (size_t)(seg * 8 + srow) * K + kt + scol, &At[seg * 512]);
      gld_lds16(Bb + (size_t)(seg * 8 + srow) * K + kt + scol, &Bt[seg * 512]);
    }
    __syncthreads();
#pragma unroll
    for (int ko = 0; ko < 64; ko += 32) {
      bf16x8 af[4], bfr[4];
#pragma unroll
      for (int mi = 0; mi < 4; ++mi)
        af[mi] = *reinterpret_cast<const bf16x8*>(&At[(wr * 64 + mi * 16 + r16) * 64 + ko + g * 8]);
#pragma unroll
      for (int ni = 0; ni < 4; ++ni)
        bfr[ni] = *reinterpret_cast<const bf16x8*>(&Bt[(wc * 64 + ni * 16 + r16) * 64 + ko + g * 8]);
#pragma unroll
      for (int mi = 0; mi < 4; ++mi)
#pragma unroll
        for (int ni = 0; ni < 4; ++ni)
          acc[mi][ni] = __builtin_amdgcn_mfma_f32_16x16x32_bf16(af[mi], bfr[ni], acc[mi][ni], 0, 0, 0);
    }
    __syncthreads();
  }

#pragma unroll
  for (int mi = 0; mi < 4; ++mi)
#pragma unroll
    for (int ni = 0; ni < 4; ++ni) {
      int row0 = bm * 128 + wr * 64 + mi * 16 + g * 4;
      int col  = bn * 128 + wc * 64 + ni * 16 + r16;
#pragma unroll
      for (int r = 0; r < 4; ++r) {
        float v = acc[mi][ni][r];
        if (BF16OUT) ((u16*)Cv)[(size_t)(row0 + r) * N + col] = f2bf(v);
        else         ((float*)Cv)[(size_t)(row0 + r) * N + col] = v;
      }
    }
}

// ---------------- GEMM: 128x64 tile (O-proj: grid 512 = 2 blocks/CU) ----
__global__ __launch_bounds__(256) void gemm_bt64(const u16* __restrict__ A,
                                                 const u16* __restrict__ B,
                                                 float* __restrict__ C,
                                                 int M, int N, int K) {
  __shared__ u16 At[128 * 64];
  __shared__ u16 Bt[64 * 64];
  const int tid  = threadIdx.x;
  const int wave = tid >> 6;
  const int lane = tid & 63;
  const int g    = lane >> 4;
  const int r16  = lane & 15;
  const int bm   = blockIdx.y;
  const int bn   = blockIdx.x;

  const u16* Ab = A + (size_t)bm * 128 * K;
  const u16* Bb = B + (size_t)bn * 64 * K;
  const int srow = lane >> 3;
  const int scol = (lane & 7) * 8;

  f32x4 acc[2][4] = {};

  for (int kt = 0; kt < K; kt += 64) {
#pragma unroll
    for (int c = 0; c < 4; ++c) {
      int seg = wave * 4 + c;
      gld_lds16(Ab + (size_t)(seg * 8 + srow) * K + kt + scol, &At[seg * 512]);
    }
#pragma unroll
    for (int c = 0; c < 2; ++c) {
      int seg = wave * 2 + c;
      gld_lds16(Bb + (size_t)(seg * 8 + srow) * K + kt + scol, &Bt[seg * 512]);
    }
    __syncthreads();
#pragma unroll
    for (int ko = 0; ko < 64; ko += 32) {
      bf16x8 af[2], bfr[4];
#pragma unroll
      for (int mi = 0; mi < 2; ++mi)
        af[mi] = *reinterpret_cast<const bf16x8*>(&At[(wave * 32 + mi * 16 + r16) * 64 + ko + g * 8]);
#pragma unroll
      for (int ni = 0; ni < 4; ++ni)
        bfr[ni] = *reinterpret_cast<const bf16x8*>(&Bt[(ni * 16 + r16) * 64 + ko + g * 8]);
#pragma unroll
      for (int mi = 0; mi < 2; ++mi)
#pragma unroll
        for (int ni = 0; ni < 4; ++ni)
          acc[mi][ni] = __builtin_amdgcn_mfma_f32_16x16x32_bf16(af[mi], bfr[ni], acc[mi][ni], 0, 0, 0);
    }
    __syncthreads();
  }

#pragma unroll
  for (int mi = 0; mi < 2; ++mi)
#pragma unroll
    for (int ni = 0; ni < 4; ++ni) {
      int row0 = bm * 128 + wave * 32 + mi * 16 + g * 4;
      int col  = bn * 64 + ni * 16 + r16;
#pragma unroll
      for (int r = 0; r < 4; ++r)
        C[(size_t)(row0 + r) * N + col] = acc[mi][ni][r];
    }
}

// ---------------- flash attention: swapped-QK^T 32x32 (R8 body) + KV-split ----
// DS-light design: no K LDS, no P LDS, 2 shuffles/tile (vs 80 DS-ops of the
// 16x16 design). SPLIT: 1024 blocks, half=n>>9 does KV [half*1024,+1024) =
// 16 tiles; 4096 waves = 4/SIMD (VGPR ~112 <= 128). Merge kernel combines.
template<bool SPLIT>
__global__ __launch_bounds__(256, 2) void attn_kernel(const u16* __restrict__ qkv,
                                                      const float* __restrict__ mask,
                                                      u16* __restrict__ AO,
                                                      float* __restrict__ ML) {
  __shared__ u16 Vt[2][64 * 64];   // [d][key] swizzled, double-buffered

  const int tid  = threadIdx.x;
  const int w    = tid >> 6;
  const int lane = tid & 63;
  const int q31  = lane & 31;
  const int hi   = lane >> 5;

  const int n0   = blockIdx.x;
  const int half = SPLIT ? (n0 >> 9) : 0;
  const int n    = SPLIT ? (n0 & 511) : n0;
  const int kv0  = half << 10;
  const int KVEND = SPLIT ? (kv0 + 1024) : SEQ;

  const int x  = n & 7;
  const int s_ = n >> 3;
  const int h  = s_ & 15;
  const int t_ = ((s_ >> 4) << 3) + x;
  const int b  = t_ >> 4;
  const int qt = t_ & 15;

  const size_t tokbase = (size_t)b * SEQ;
  const int qrow0 = qt * 128 + w * 32;
  const int q_lane = qrow0 + q31;

  bf16x8 qf[4];
  {
    const u16* qb = qkv + ((tokbase + q_lane) * 3 + 0) * HID + h * HD + 8 * hi;
#pragma unroll
    for (int s = 0; s < 4; ++s)
      qf[s] = *reinterpret_cast<const bf16x8*>(qb + 16 * s);
  }
  const float* mrowp = mask + ((size_t)b * SEQ + q_lane) * SEQ;

  f32x16 oa0 = {}, oa1 = {};
  float mold = -3.0e38f, lsum = 0.f;

  const int vkey = tid >> 2;
  const int vd3  = tid & 3;

  // ---- prologue: K frags, V regs, mask regs for first tile; stage Vt[0] ----
  bf16x8 kf[2][4];
#pragma unroll
  for (int t = 0; t < 2; ++t) {
    const u16* kb_ = qkv + ((tokbase + kv0 + 32 * t + q31) * 3 + 1) * HID + h * HD + 8 * hi;
#pragma unroll
    for (int s = 0; s < 4; ++s)
      kf[t][s] = *reinterpret_cast<const bf16x8*>(kb_ + 16 * s);
  }
  u16x8 v0, v1;
  {
    const u16* vp = qkv + ((tokbase + kv0 + vkey) * 3 + 2) * HID + h * HD + vd3 * 16;
    v0 = *reinterpret_cast<const u16x8*>(vp);
    v1 = *reinterpret_cast<const u16x8*>(vp + 8);
  }
  float4 mreg[8];
#pragma unroll
  for (int t = 0; t < 2; ++t)
#pragma unroll
    for (int a = 0; a < 4; ++a)
      mreg[t * 4 + a] = *reinterpret_cast<const float4*>(mrowp + kv0 + 32 * t + 8 * a + 4 * hi);
#pragma unroll
  for (int j = 0; j < 16; ++j) {
    u16 val = (j < 8) ? (u16)v0[j] : (u16)v1[j - 8];
    int row = vd3 * 16 + j;
    int sV  = (vd3 + (j & 7)) & 7;
    Vt[0][row * 64 + (((vkey >> 3) ^ sV) << 3) + (vkey & 7)] = val;
  }
  lds_barrier();   // Vt[0] visible

#pragma unroll 1
  for (int kb = kv0; kb < KVEND; kb += 64) {
    const int cur = (kb >> 6) & 1;
    const int nxt = cur ^ 1;
    const bool more = (kb + 64) < KVEND;

    // ---- S^T = K * Q^T ----
    f32x16 sa0 = {}, sa1 = {};
#pragma unroll
    for (int s = 0; s < 4; ++s)
      sa0 = __builtin_amdgcn_mfma_f32_32x32x16_bf16(kf[0][s], qf[s], sa0, 0, 0, 0);
#pragma unroll
    for (int s = 0; s < 4; ++s)
      sa1 = __builtin_amdgcn_mfma_f32_32x32x16_bf16(kf[1][s], qf[s], sa1, 0, 0, 0);

    // ---- issue next tile's K frags + V regs ----
    if (more) {
#pragma unroll
      for (int t = 0; t < 2; ++t) {
        const u16* kb_ = qkv + ((tokbase + kb + 64 + 32 * t + q31) * 3 + 1) * HID + h * HD + 8 * hi;
#pragma unroll
        for (int s = 0; s < 4; ++s)
          kf[t][s] = *reinterpret_cast<const bf16x8*>(kb_ + 16 * s);
      }
      const u16* vp = qkv + ((tokbase + kb + 64 + vkey) * 3 + 2) * HID + h * HD + vd3 * 16;
      v0 = *reinterpret_cast<const u16x8*>(vp);
      v1 = *reinterpret_cast<const u16x8*>(vp + 8);
    }

    // ---- scale + mask from prefetched regs ----
#pragma unroll
    for (int t = 0; t < 2; ++t) {
      f32x16& sa = t ? sa1 : sa0;
#pragma unroll
      for (int r = 0; r < 16; ++r)
        sa[r] = sa[r] * 0.125f +
                reinterpret_cast<const float*>(&mreg[t * 4 + (r >> 2)])[r & 3];
    }
    // ---- prefetch next tile's mask ----
    if (more) {
#pragma unroll
      for (int t = 0; t < 2; ++t)
#pragma unroll
        for (int a = 0; a < 4; ++a)
          mreg[t * 4 + a] = *reinterpret_cast<const float4*>(
              mrowp + kb + 64 + 32 * t + 8 * a + 4 * hi);
    }

    // ---- lane-local online softmax ----
    float mx = -3.0e38f;
#pragma unroll
    for (int r = 0; r < 16; ++r) mx = fmaxf(mx, sa0[r]);
#pragma unroll
    for (int r = 0; r < 16; ++r) mx = fmaxf(mx, sa1[r]);
    mx = fmaxf(mx, __shfl_xor(mx, 32));
    float mnew  = fmaxf(mold, mx);
    float alpha = __expf(mold - mnew);
    mold = mnew;
#pragma unroll
    for (int r = 0; r < 16; ++r) { oa0[r] *= alpha; oa1[r] *= alpha; }
    float ps = 0.f;
#pragma unroll
    for (int r = 0; r < 16; ++r) { float p = __expf(sa0[r] - mnew); sa0[r] = p; ps += p; }
#pragma unroll
    for (int r = 0; r < 16; ++r) { float p = __expf(sa1[r] - mnew); sa1[r] = p; ps += p; }
    ps += __shfl_xor(ps, 32);
    lsum = lsum * alpha + ps;

    // ---- PV ----
#pragma unroll
    for (int c = 0; c < 4; ++c) {
      const int cl = c & 1;
      const f32x16& sa = (c >> 1) ? sa1 : sa0;
      unsigned X0 = cvtpk(sa[8 * cl + 0], sa[8 * cl + 1]);
      unsigned X1 = cvtpk(sa[8 * cl + 2], sa[8 * cl + 3]);
      unsigned X2 = cvtpk(sa[8 * cl + 4], sa[8 * cl + 5]);
      unsigned X3 = cvtpk(sa[8 * cl + 6], sa[8 * cl + 7]);
      pswap(X0, X2);
      pswap(X1, X3);
      union { unsigned u[4]; bf16x8 v; } pb;
      pb.u[0] = X0; pb.u[1] = X1; pb.u[2] = X2; pb.u[3] = X3;
#pragma unroll
      for (int dt = 0; dt < 2; ++dt) {
        int row  = dt * 32 + q31;
        int srow = ((row >> 4) + (row & 7)) & 7;
        bf16x8 va = *reinterpret_cast<const bf16x8*>(
            &Vt[cur][row * 64 + (((2 * c + hi) ^ srow) << 3)]);
        f32x16& oa = dt ? oa1 : oa0;
        oa = __builtin_amdgcn_mfma_f32_32x32x16_bf16(va, pb.v, oa, 0, 0, 0);
      }
    }

    // ---- stage next V tile ----
    if (more) {
#pragma unroll
      for (int j = 0; j < 16; ++j) {
        u16 val = (j < 8) ? (u16)v0[j] : (u16)v1[j - 8];
        int row = vd3 * 16 + j;
        int sV  = (vd3 + (j & 7)) & 7;
        Vt[nxt][row * 64 + (((vkey >> 3) ^ sV) << 3) + (vkey & 7)] = val;
      }
    }
    lds_barrier();   // Vt[nxt] visible; reads of Vt[cur] done; no vmcnt drain
  }

  // ---- finalize: normalized O to AO + half-offset; (m,l) in SPLIT mode ----
  float inv_l = 1.0f / lsum;
  u16* ob = AO + (size_t)half * NTOK * HID + (tokbase + q_lane) * HID + h * HD;
#pragma unroll
  for (int dt = 0; dt < 2; ++dt) {
    const f32x16& oa = dt ? oa1 : oa0;
#pragma unroll
    for (int a = 0; a < 4; ++a) {
      u16x4 pk_;
#pragma unroll
      for (int i = 0; i < 4; ++i) pk_[i] = f2bf(oa[4 * a + i] * inv_l);
      *reinterpret_cast<u16x4*>(ob + dt * 32 + 8 * a + 4 * hi) = pk_;
    }
  }
  if (SPLIT && hi == 0) {
    size_t mi_ = ((tokbase + q_lane) * NHEAD + h) * 4 + half * 2;
    ML[mi_ + 0] = mold;
    ML[mi_ + 1] = lsum;
  }
}

// ---------------- flash-combine of the two KV halves (in place into P0) ----
__global__ __launch_bounds__(256) void merge_kernel(u16* __restrict__ P0,
                                                    const u16* __restrict__ P1,
                                                    const float* __restrict__ ML) {
  int t  = blockIdx.x * 256 + threadIdx.x;
  int i  = t >> 3;                 // tok*16 + h
  int d0 = (t & 7) * 8;
  int tok = i >> 4, h = i & 15;
  size_t off = (size_t)tok * HID + h * 64 + d0;
  float m0 = ML[(size_t)i * 4 + 0], l0 = ML[(size_t)i * 4 + 1];
  float m1 = ML[(size_t)i * 4 + 2], l1 = ML[(size_t)i * 4 + 3];
  float ms = fmaxf(m0, m1);
  float w0 = l0 * __expf(m0 - ms);
  float w1 = l1 * __expf(m1 - ms);
  float inv = 1.0f / (w0 + w1);
  w0 *= inv; w1 *= inv;
  u16x8 a = *reinterpret_cast<const u16x8*>(P0 + off);
  u16x8 c = *reinterpret_cast<const u16x8*>(P1 + off);
  u16x8 o;
#pragma unroll
  for (int j = 0; j < 8; ++j)
    o[j] = f2bf(w0 * bf2f((u16)a[j]) + w1 * bf2f((u16)c[j]));
  *reinterpret_cast<u16x8*>(P0 + off) = o;
}

// ---------------- launcher ----------------
extern "C" void kernel_launch(void* const* d_in, const int* in_sizes, int n_in,
                              void* d_out, int out_size, void* d_ws, size_t ws_size,
                              hipStream_t stream) {
  (void)in_sizes; (void)n_in; (void)out_size;
  const float* hs   = (const float*)d_in[0];
  const float* mask = (const float*)d_in[1];
  const float* wqkv = (const float*)d_in[2];
  const float* wo   = (const float*)d_in[3];
  float* out = (float*)d_out;

  char* ws   = (char*)d_ws;
  u16* Xb    = (u16*)(ws);                        // 8 MiB
  u16* Wqkvb = (u16*)(ws + 8u  * 1024 * 1024);    // 6 MiB
  u16* Wob   = (u16*)(ws + 14u * 1024 * 1024);    // 2 MiB
  u16* QKVb  = (u16*)(ws + 16u * 1024 * 1024);    // 24 MiB
  u16* P0    = (u16*)(ws + 40u * 1024 * 1024);    // 8 MiB
  u16* P1    = P0 + (size_t)NTOK * HID;           // 8 MiB (contiguous)
  float* ML  = (float*)(ws + 56u * 1024 * 1024);  // 1 MiB

  const bool split = ws_size >= 57u * 1024 * 1024;

  cvt3_kernel<<<8192, 256, 0, stream>>>(hs, Xb, wqkv, Wqkvb, wo, Wob);
  gemm_bt<true><<<dim3(3072 / 128, 4096 / 128), 256, 0, stream>>>(Xb, Wqkvb, QKVb, NTOK, 3072, HID);

  if (split) {
    attn_kernel<true><<<1024, 256, 0, stream>>>(QKVb, mask, P0, ML);
    merge_kernel<<<2048, 256, 0, stream>>>(P0, P1, ML);
  } else {
    attn_kernel<false><<<512, 256, 0, stream>>>(QKVb, mask, P0, ML);
  }

  gemm_bt64<<<dim3(1024 / 64, 4096 / 128), 256, 0, stream>>>(P0, Wob, out, NTOK, 1024, HID);
}

// Round 15
// 182.657 us; speedup vs baseline: 1.2024x; 1.2024x over previous
//
#include <hip/hip_runtime.h>

typedef unsigned short u16;
using bf16x8 = __attribute__((ext_vector_type(8))) __bf16;
using f32x4  = __attribute__((ext_vector_type(4))) float;
using u16x8  = __attribute__((ext_vector_type(8))) unsigned short;
using u16x4  = __attribute__((ext_vector_type(4))) unsigned short;

#define SEQ   2048
#define HID   1024
#define NHEAD 16
#define HD    64
#define BATCH 2
#define NTOK  4096   // BATCH*SEQ

__device__ __forceinline__ u16 f2bf(float f) {
  unsigned u = __builtin_bit_cast(unsigned, f);
  u += 0x7fffu + ((u >> 16) & 1u);
  return (u16)(u >> 16);
}

__device__ __forceinline__ void gld_lds16(const void* g, void* l) {
  __builtin_amdgcn_global_load_lds(
      (__attribute__((address_space(1))) void*)(__UINTPTR_TYPE__)g,
      (__attribute__((address_space(3))) void*)l, 16, 0, 0);
}

// VALU-pipe cross-lane rotate within a 16-lane DPP row (replaces ds_swizzle
// shuffles). ctrl: row_ror:N = 0x120+N. Compiler inserts DPP hazard nops.
template<int CTRL>
__device__ __forceinline__ float row_ror(float x) {
  int xi = __builtin_bit_cast(int, x);
  int r  = __builtin_amdgcn_update_dpp(xi, xi, CTRL, 0xf, 0xf, false);
  return __builtin_bit_cast(float, r);
}
// full 16-lane rotate-reduce: after 4 steps every lane holds the row total
__device__ __forceinline__ float rowmax16(float x) {
  x = fmaxf(x, row_ror<0x121>(x));
  x = fmaxf(x, row_ror<0x122>(x));
  x = fmaxf(x, row_ror<0x124>(x));
  x = fmaxf(x, row_ror<0x128>(x));
  return x;
}
__device__ __forceinline__ float rowsum16(float x) {
  x += row_ror<0x121>(x);
  x += row_ror<0x122>(x);
  x += row_ror<0x124>(x);
  x += row_ror<0x128>(x);
  return x;
}

// ---------------- fused fp32 -> bf16 convert (X, Wqkv, Wo in one launch) ----
__global__ __launch_bounds__(256) void cvt3_kernel(const float* __restrict__ a, u16* __restrict__ oa,
                                                   const float* __restrict__ b, u16* __restrict__ ob,
                                                   const float* __restrict__ c, u16* __restrict__ oc) {
  const float* in; u16* out; int off;
  int bid = blockIdx.x;
  if (bid < 4096)      { in = a; out = oa; off = bid; }
  else if (bid < 7168) { in = b; out = ob; off = bid - 4096; }
  else                 { in = c; out = oc; off = bid - 7168; }
  int i = (off * 256 + threadIdx.x) * 4;
  float4 v = *reinterpret_cast<const float4*>(in + i);
  u16x4 o = { f2bf(v.x), f2bf(v.y), f2bf(v.z), f2bf(v.w) };
  *reinterpret_cast<u16x4*>(out + i) = o;
}

// ---------------- GEMM: C[M,N] = A[M,K] * B[N,K]^T, 128x128 ----------------
template<bool BF16OUT>
__global__ __launch_bounds__(256) void gemm_bt(const u16* __restrict__ A,
                                               const u16* __restrict__ B,
                                               void* __restrict__ Cv,
                                               int M, int N, int K) {
  __shared__ u16 At[128 * 64];
  __shared__ u16 Bt[128 * 64];
  const int tid  = threadIdx.x;
  const int wave = tid >> 6;
  const int lane = tid & 63;
  const int g    = lane >> 4;
  const int r16  = lane & 15;
  const int wr   = wave >> 1;
  const int wc   = wave & 1;
  const int bm   = blockIdx.y;
  const int bn   = blockIdx.x;

  const u16* Ab = A + (size_t)bm * 128 * K;
  const u16* Bb = B + (size_t)bn * 128 * K;
  const int srow = lane >> 3;
  const int scol = (lane & 7) * 8;

  f32x4 acc[4][4] = {};

  for (int kt = 0; kt < K; kt += 64) {
#pragma unroll
    for (int c = 0; c < 4; ++c) {
      int seg = wave * 4 + c;
      gld_lds16(Ab + (size_t)(seg * 8 + srow) * K + kt + scol, &At[seg * 512]);
      gld_lds16(Bb + (size_t)(seg * 8 + srow) * K + kt + scol, &Bt[seg * 512]);
    }
    __syncthreads();
#pragma unroll
    for (int ko = 0; ko < 64; ko += 32) {
      bf16x8 af[4], bfr[4];
#pragma unroll
      for (int mi = 0; mi < 4; ++mi)
        af[mi] = *reinterpret_cast<const bf16x8*>(&At[(wr * 64 + mi * 16 + r16) * 64 + ko + g * 8]);
#pragma unroll
      for (int ni = 0; ni < 4; ++ni)
        bfr[ni] = *reinterpret_cast<const bf16x8*>(&Bt[(wc * 64 + ni * 16 + r16) * 64 + ko + g * 8]);
#pragma unroll
      for (int mi = 0; mi < 4; ++mi)
#pragma unroll
        for (int ni = 0; ni < 4; ++ni)
          acc[mi][ni] = __builtin_amdgcn_mfma_f32_16x16x32_bf16(af[mi], bfr[ni], acc[mi][ni], 0, 0, 0);
    }
    __syncthreads();
  }

#pragma unroll
  for (int mi = 0; mi < 4; ++mi)
#pragma unroll
    for (int ni = 0; ni < 4; ++ni) {
      int row0 = bm * 128 + wr * 64 + mi * 16 + g * 4;
      int col  = bn * 128 + wc * 64 + ni * 16 + r16;
#pragma unroll
      for (int r = 0; r < 4; ++r) {
        float v = acc[mi][ni][r];
        if (BF16OUT) ((u16*)Cv)[(size_t)(row0 + r) * N + col] = f2bf(v);
        else         ((float*)Cv)[(size_t)(row0 + r) * N + col] = v;
      }
    }
}

// ---------------- GEMM: 128x64 tile (O-proj: grid 512 = 2 blocks/CU) ----
__global__ __launch_bounds__(256) void gemm_bt64(const u16* __restrict__ A,
                                                 const u16* __restrict__ B,
                                                 float* __restrict__ C,
                                                 int M, int N, int K) {
  __shared__ u16 At[128 * 64];
  __shared__ u16 Bt[64 * 64];
  const int tid  = threadIdx.x;
  const int wave = tid >> 6;
  const int lane = tid & 63;
  const int g    = lane >> 4;
  const int r16  = lane & 15;
  const int bm   = blockIdx.y;
  const int bn   = blockIdx.x;

  const u16* Ab = A + (size_t)bm * 128 * K;
  const u16* Bb = B + (size_t)bn * 64 * K;
  const int srow = lane >> 3;
  const int scol = (lane & 7) * 8;

  f32x4 acc[2][4] = {};

  for (int kt = 0; kt < K; kt += 64) {
#pragma unroll
    for (int c = 0; c < 4; ++c) {
      int seg = wave * 4 + c;
      gld_lds16(Ab + (size_t)(seg * 8 + srow) * K + kt + scol, &At[seg * 512]);
    }
#pragma unroll
    for (int c = 0; c < 2; ++c) {
      int seg = wave * 2 + c;
      gld_lds16(Bb + (size_t)(seg * 8 + srow) * K + kt + scol, &Bt[seg * 512]);
    }
    __syncthreads();
#pragma unroll
    for (int ko = 0; ko < 64; ko += 32) {
      bf16x8 af[2], bfr[4];
#pragma unroll
      for (int mi = 0; mi < 2; ++mi)
        af[mi] = *reinterpret_cast<const bf16x8*>(&At[(wave * 32 + mi * 16 + r16) * 64 + ko + g * 8]);
#pragma unroll
      for (int ni = 0; ni < 4; ++ni)
        bfr[ni] = *reinterpret_cast<const bf16x8*>(&Bt[(ni * 16 + r16) * 64 + ko + g * 8]);
#pragma unroll
      for (int mi = 0; mi < 2; ++mi)
#pragma unroll
        for (int ni = 0; ni < 4; ++ni)
          acc[mi][ni] = __builtin_amdgcn_mfma_f32_16x16x32_bf16(af[mi], bfr[ni], acc[mi][ni], 0, 0, 0);
    }
    __syncthreads();
  }

#pragma unroll
  for (int mi = 0; mi < 2; ++mi)
#pragma unroll
    for (int ni = 0; ni < 4; ++ni) {
      int row0 = bm * 128 + wave * 32 + mi * 16 + g * 4;
      int col  = bn * 64 + ni * 16 + r16;
#pragma unroll
      for (int r = 0; r < 4; ++r)
        C[(size_t)(row0 + r) * N + col] = acc[mi][ni][r];
    }
}

// ---------------- flash attention (R11 + DPP rotate-reduce softmax) ----------------
__global__ __launch_bounds__(256, 4) void attn_kernel(const u16* __restrict__ qkv,
                                                      const float* __restrict__ mask,
                                                      u16* __restrict__ AO) {
  __shared__ u16 Kt[2][64 * 64];   // [key][d]   swizzled, double-buffered
  __shared__ u16 Vt[64 * 64];      // [d][key]   swizzled (transposed)
  __shared__ u16 Pl[4][16 * 64];   // per-wave P swizzled (wave-private)

  const int tid  = threadIdx.x;
  const int w    = tid >> 6;
  const int lane = tid & 63;
  const int g    = lane >> 4;
  const int r16  = lane & 15;

  const int n  = blockIdx.x;
  const int x  = n & 7;
  const int s_ = n >> 3;
  const int h  = s_ & 15;
  const int t_ = ((s_ >> 4) << 3) + x;
  const int b  = t_ >> 5;
  const int qt = t_ & 31;

  const size_t tokbase = (size_t)b * SEQ;

  bf16x8 aq[2];
  {
    int qrow = qt * 64 + w * 16 + r16;
#pragma unroll
    for (int ko = 0; ko < 2; ++ko)
      aq[ko] = *reinterpret_cast<const bf16x8*>(
          qkv + ((tokbase + qrow) * 3 + 0) * HID + h * HD + ko * 32 + g * 8);
  }

  f32x4 o[4] = {};
  float mrow[4], lrow[4];
#pragma unroll
  for (int r = 0; r < 4; ++r) { mrow[r] = -3.0e38f; lrow[r] = 0.f; }

  const int srowK = lane >> 3;        // 0..7
  const int vkey  = tid >> 2;         // 0..63
  const int vd3   = tid & 3;

#define STAGE_K(buf, kb)                                                        \
  {                                                                             \
    _Pragma("unroll")                                                           \
    for (int c = 0; c < 2; ++c) {                                               \
      int seg = w * 2 + c;                                                      \
      int sK  = ((seg >> 1) + srowK) & 7;                                       \
      int srcc = (lane & 7) ^ sK;                                               \
      gld_lds16(qkv + ((tokbase + (kb) + seg * 8 + srowK) * 3 + 1) * HID +      \
                    h * HD + srcc * 8,                                          \
                &Kt[buf][seg * 512]);                                           \
    }                                                                           \
  }

  // ---- prologue: K tile 0 in flight ----
  STAGE_K(0, 0);

#pragma unroll 1
  for (int kb = 0; kb < SEQ; kb += 64) {
    const int cur = (kb >> 6) & 1;
    const int nxt = cur ^ 1;
    const bool more = (kb + 64) < SEQ;

    // ---- reg loads for THIS tile: mask + V ----
    float mpre[4][4];
#pragma unroll
    for (int r = 0; r < 4; ++r) {
      int q = qt * 64 + w * 16 + g * 4 + r;
      const float* mp = mask + ((size_t)b * SEQ + q) * SEQ + kb;
#pragma unroll
      for (int ni = 0; ni < 4; ++ni) mpre[r][ni] = mp[ni * 16 + r16];
    }
    const u16* vp = qkv + ((tokbase + kb + vkey) * 3 + 2) * HID + h * HD + vd3 * 16;
    u16x8 v0 = *reinterpret_cast<const u16x8*>(vp);
    u16x8 v1 = *reinterpret_cast<const u16x8*>(vp + 8);

    __syncthreads();   // A: prev-tile LDS reads done; drains vmcnt

    // ---- V -> LDS transposed, swizzled scalar writes ----
#pragma unroll
    for (int j = 0; j < 16; ++j) {
      u16 val = (j < 8) ? (u16)v0[j] : (u16)v1[j - 8];
      int row = vd3 * 16 + j;
      int sV  = (vd3 + (j & 7)) & 7;
      Vt[row * 64 + (((vkey >> 3) ^ sV) << 3) + (vkey & 7)] = val;
    }
    __syncthreads();   // B: Vt + Kt[cur] visible to all waves

    // ---- S = Q K^T on Kt[cur] ----
    f32x4 sf[4] = {};
    __builtin_amdgcn_s_setprio(1);
#pragma unroll
    for (int ko = 0; ko < 2; ++ko) {
      bf16x8 bk[4];
#pragma unroll
      for (int ni = 0; ni < 4; ++ni) {
        int row = ni * 16 + r16;
        int sK  = (ni + (r16 & 7)) & 7;
        bk[ni] = *reinterpret_cast<const bf16x8*>(
            &Kt[cur][row * 64 + (((ko * 4 + g) ^ sK) << 3)]);
      }
#pragma unroll
      for (int ni = 0; ni < 4; ++ni)
        sf[ni] = __builtin_amdgcn_mfma_f32_16x16x32_bf16(aq[ko], bk[ni], sf[ni], 0, 0, 0);
    }
    __builtin_amdgcn_s_setprio(0);

    // ---- online softmax: DPP rotate-reduce (VALU pipe, no DS ops) ----
#pragma unroll
    for (int r = 0; r < 4; ++r) {
      float mx = -3.0e38f;
#pragma unroll
      for (int ni = 0; ni < 4; ++ni) {
        float sv = sf[ni][r] * 0.125f + mpre[r][ni];
        sf[ni][r] = sv;
        mx = fmaxf(mx, sv);
      }
      mx = rowmax16(mx);
      float mnew  = fmaxf(mrow[r], mx);
      float alpha = __expf(mrow[r] - mnew);
      mrow[r] = mnew;
      float s = 0.f;
#pragma unroll
      for (int ni = 0; ni < 4; ++ni) {
        float p = __expf(sf[ni][r] - mnew);
        sf[ni][r] = p;
        s += p;
      }
      s = rowsum16(s);
      lrow[r] = lrow[r] * alpha + s;
#pragma unroll
      for (int di = 0; di < 4; ++di) o[di][r] *= alpha;
      int prow = g * 4 + r;
      int sP   = prow & 7;
#pragma unroll
      for (int ni = 0; ni < 4; ++ni) {
        int chunk = ni * 2 + (r16 >> 3);
        Pl[w][prow * 64 + ((chunk ^ sP) << 3) + (r16 & 7)] = f2bf(sf[ni][r]);
      }
    }
    // no barrier: Pl[w] is wave-private; lgkmcnt orders write->read

    // ---- prefetch next K tile (zero-register) ----
    if (more) STAGE_K(nxt, kb + 64);

    // ---- O += P V ----
    __builtin_amdgcn_s_setprio(1);
#pragma unroll
    for (int kk = 0; kk < 2; ++kk) {
      bf16x8 pa, bv[4];
      pa = *reinterpret_cast<const bf16x8*>(
          &Pl[w][r16 * 64 + (((kk * 4 + g) ^ (r16 & 7)) << 3)]);
#pragma unroll
      for (int di = 0; di < 4; ++di) {
        int row = di * 16 + r16;
        int sV  = (di + (r16 & 7)) & 7;
        bv[di] = *reinterpret_cast<const bf16x8*>(
            &Vt[row * 64 + (((kk * 4 + g) ^ sV) << 3)]);
      }
#pragma unroll
      for (int di = 0; di < 4; ++di)
        o[di] = __builtin_amdgcn_mfma_f32_16x16x32_bf16(pa, bv[di], o[di], 0, 0, 0);
    }
    __builtin_amdgcn_s_setprio(0);
  }

  // finalize
#pragma unroll
  for (int di = 0; di < 4; ++di)
#pragma unroll
    for (int r = 0; r < 4; ++r) {
      int srow = qt * 64 + w * 16 + g * 4 + r;
      float val = o[di][r] / lrow[r];
      AO[(tokbase + srow) * HID + h * HD + di * 16 + r16] = f2bf(val);
    }
#undef STAGE_K
}

// ---------------- launcher ----------------
extern "C" void kernel_launch(void* const* d_in, const int* in_sizes, int n_in,
                              void* d_out, int out_size, void* d_ws, size_t ws_size,
                              hipStream_t stream) {
  (void)in_sizes; (void)n_in; (void)out_size; (void)ws_size;
  const float* hs   = (const float*)d_in[0];
  const float* mask = (const float*)d_in[1];
  const float* wqkv = (const float*)d_in[2];
  const float* wo   = (const float*)d_in[3];
  float* out = (float*)d_out;

  char* ws   = (char*)d_ws;
  u16* Xb    = (u16*)(ws);                        // 8 MiB
  u16* Wqkvb = (u16*)(ws + 8u  * 1024 * 1024);    // 6 MiB
  u16* Wob   = (u16*)(ws + 14u * 1024 * 1024);    // 2 MiB
  u16* QKVb  = (u16*)(ws + 16u * 1024 * 1024);    // 24 MiB
  u16* AOb   = (u16*)(ws + 40u * 1024 * 1024);    // 8 MiB

  cvt3_kernel<<<8192, 256, 0, stream>>>(hs, Xb, wqkv, Wqkvb, wo, Wob);

  gemm_bt<true><<<dim3(3072 / 128, 4096 / 128), 256, 0, stream>>>(Xb, Wqkvb, QKVb, NTOK, 3072, HID);
  attn_kernel  <<<1024, 256, 0, stream>>>(QKVb, mask, AOb);
  gemm_bt64    <<<dim3(1024 / 64, 4096 / 128), 256, 0, stream>>>(AOb, Wob, out, NTOK, 1024, HID);
}

// Round 16
// 174.871 us; speedup vs baseline: 1.2559x; 1.0445x over previous
//
#include <hip/hip_runtime.h>

typedef unsigned short u16;
using bf16x8 = __attribute__((ext_vector_type(8))) __bf16;
using f32x4  = __attribute__((ext_vector_type(4))) float;
using u16x8  = __attribute__((ext_vector_type(8))) unsigned short;
using u16x4  = __attribute__((ext_vector_type(4))) unsigned short;

#define SEQ   2048
#define HID   1024
#define NHEAD 16
#define HD    64
#define BATCH 2
#define NTOK  4096   // BATCH*SEQ

__device__ __forceinline__ u16 f2bf(float f) {
  unsigned u = __builtin_bit_cast(unsigned, f);
  u += 0x7fffu + ((u >> 16) & 1u);
  return (u16)(u >> 16);
}

__device__ __forceinline__ void gld_lds16(const void* g, void* l) {
  __builtin_amdgcn_global_load_lds(
      (__attribute__((address_space(1))) void*)(__UINTPTR_TYPE__)g,
      (__attribute__((address_space(3))) void*)l, 16, 0, 0);
}

// pack two f32 -> two bf16 (RNE) in one VALU op
__device__ __forceinline__ unsigned cvtpk(float lo, float hi) {
  unsigned r;
  asm("v_cvt_pk_bf16_f32 %0, %1, %2" : "=v"(r) : "v"(lo), "v"(hi));
  return r;
}

// VALU-pipe cross-lane rotate within a 16-lane DPP row (replaces ds_swizzle
// shuffles). ctrl: row_ror:N = 0x120+N. Compiler inserts DPP hazard nops.
template<int CTRL>
__device__ __forceinline__ float row_ror(float x) {
  int xi = __builtin_bit_cast(int, x);
  int r  = __builtin_amdgcn_update_dpp(xi, xi, CTRL, 0xf, 0xf, false);
  return __builtin_bit_cast(float, r);
}
__device__ __forceinline__ float rowmax16(float x) {
  x = fmaxf(x, row_ror<0x121>(x));
  x = fmaxf(x, row_ror<0x122>(x));
  x = fmaxf(x, row_ror<0x124>(x));
  x = fmaxf(x, row_ror<0x128>(x));
  return x;
}
__device__ __forceinline__ float rowsum16(float x) {
  x += row_ror<0x121>(x);
  x += row_ror<0x122>(x);
  x += row_ror<0x124>(x);
  x += row_ror<0x128>(x);
  return x;
}

// ---------------- fused fp32 -> bf16 convert (X, Wqkv, Wo in one launch) ----
__global__ __launch_bounds__(256) void cvt3_kernel(const float* __restrict__ a, u16* __restrict__ oa,
                                                   const float* __restrict__ b, u16* __restrict__ ob,
                                                   const float* __restrict__ c, u16* __restrict__ oc) {
  const float* in; u16* out; int off;
  int bid = blockIdx.x;
  if (bid < 4096)      { in = a; out = oa; off = bid; }
  else if (bid < 7168) { in = b; out = ob; off = bid - 4096; }
  else                 { in = c; out = oc; off = bid - 7168; }
  int i = (off * 256 + threadIdx.x) * 4;
  float4 v = *reinterpret_cast<const float4*>(in + i);
  u16x4 o = { f2bf(v.x), f2bf(v.y), f2bf(v.z), f2bf(v.w) };
  *reinterpret_cast<u16x4*>(out + i) = o;
}

// ---------------- GEMM: C[M,N] = A[M,K] * B[N,K]^T, 128x128 ----------------
template<bool BF16OUT>
__global__ __launch_bounds__(256) void gemm_bt(const u16* __restrict__ A,
                                               const u16* __restrict__ B,
                                               void* __restrict__ Cv,
                                               int M, int N, int K) {
  __shared__ u16 At[128 * 64];
  __shared__ u16 Bt[128 * 64];
  const int tid  = threadIdx.x;
  const int wave = tid >> 6;
  const int lane = tid & 63;
  const int g    = lane >> 4;
  const int r16  = lane & 15;
  const int wr   = wave >> 1;
  const int wc   = wave & 1;
  const int bm   = blockIdx.y;
  const int bn   = blockIdx.x;

  const u16* Ab = A + (size_t)bm * 128 * K;
  const u16* Bb = B + (size_t)bn * 128 * K;
  const int srow = lane >> 3;
  const int scol = (lane & 7) * 8;

  f32x4 acc[4][4] = {};

  for (int kt = 0; kt < K; kt += 64) {
#pragma unroll
    for (int c = 0; c < 4; ++c) {
      int seg = wave * 4 + c;
      gld_lds16(Ab + (size_t)(seg * 8 + srow) * K + kt + scol, &At[seg * 512]);
      gld_lds16(Bb + (size_t)(seg * 8 + srow) * K + kt + scol, &Bt[seg * 512]);
    }
    __syncthreads();
#pragma unroll
    for (int ko = 0; ko < 64; ko += 32) {
      bf16x8 af[4], bfr[4];
#pragma unroll
      for (int mi = 0; mi < 4; ++mi)
        af[mi] = *reinterpret_cast<const bf16x8*>(&At[(wr * 64 + mi * 16 + r16) * 64 + ko + g * 8]);
#pragma unroll
      for (int ni = 0; ni < 4; ++ni)
        bfr[ni] = *reinterpret_cast<const bf16x8*>(&Bt[(wc * 64 + ni * 16 + r16) * 64 + ko + g * 8]);
#pragma unroll
      for (int mi = 0; mi < 4; ++mi)
#pragma unroll
        for (int ni = 0; ni < 4; ++ni)
          acc[mi][ni] = __builtin_amdgcn_mfma_f32_16x16x32_bf16(af[mi], bfr[ni], acc[mi][ni], 0, 0, 0);
    }
    __syncthreads();
  }

#pragma unroll
  for (int mi = 0; mi < 4; ++mi)
#pragma unroll
    for (int ni = 0; ni < 4; ++ni) {
      int row0 = bm * 128 + wr * 64 + mi * 16 + g * 4;
      int col  = bn * 128 + wc * 64 + ni * 16 + r16;
#pragma unroll
      for (int r = 0; r < 4; ++r) {
        float v = acc[mi][ni][r];
        if (BF16OUT) ((u16*)Cv)[(size_t)(row0 + r) * N + col] = f2bf(v);
        else         ((float*)Cv)[(size_t)(row0 + r) * N + col] = v;
      }
    }
}

// ---------------- GEMM: 128x64 tile (O-proj: grid 512 = 2 blocks/CU) ----
__global__ __launch_bounds__(256) void gemm_bt64(const u16* __restrict__ A,
                                                 const u16* __restrict__ B,
                                                 float* __restrict__ C,
                                                 int M, int N, int K) {
  __shared__ u16 At[128 * 64];
  __shared__ u16 Bt[64 * 64];
  const int tid  = threadIdx.x;
  const int wave = tid >> 6;
  const int lane = tid & 63;
  const int g    = lane >> 4;
  const int r16  = lane & 15;
  const int bm   = blockIdx.y;
  const int bn   = blockIdx.x;

  const u16* Ab = A + (size_t)bm * 128 * K;
  const u16* Bb = B + (size_t)bn * 64 * K;
  const int srow = lane >> 3;
  const int scol = (lane & 7) * 8;

  f32x4 acc[2][4] = {};

  for (int kt = 0; kt < K; kt += 64) {
#pragma unroll
    for (int c = 0; c < 4; ++c) {
      int seg = wave * 4 + c;
      gld_lds16(Ab + (size_t)(seg * 8 + srow) * K + kt + scol, &At[seg * 512]);
    }
#pragma unroll
    for (int c = 0; c < 2; ++c) {
      int seg = wave * 2 + c;
      gld_lds16(Bb + (size_t)(seg * 8 + srow) * K + kt + scol, &Bt[seg * 512]);
    }
    __syncthreads();
#pragma unroll
    for (int ko = 0; ko < 64; ko += 32) {
      bf16x8 af[2], bfr[4];
#pragma unroll
      for (int mi = 0; mi < 2; ++mi)
        af[mi] = *reinterpret_cast<const bf16x8*>(&At[(wave * 32 + mi * 16 + r16) * 64 + ko + g * 8]);
#pragma unroll
      for (int ni = 0; ni < 4; ++ni)
        bfr[ni] = *reinterpret_cast<const bf16x8*>(&Bt[(ni * 16 + r16) * 64 + ko + g * 8]);
#pragma unroll
      for (int mi = 0; mi < 2; ++mi)
#pragma unroll
        for (int ni = 0; ni < 4; ++ni)
          acc[mi][ni] = __builtin_amdgcn_mfma_f32_16x16x32_bf16(af[mi], bfr[ni], acc[mi][ni], 0, 0, 0);
    }
    __syncthreads();
  }

#pragma unroll
  for (int mi = 0; mi < 2; ++mi)
#pragma unroll
    for (int ni = 0; ni < 4; ++ni) {
      int row0 = bm * 128 + wave * 32 + mi * 16 + g * 4;
      int col  = bn * 64 + ni * 16 + r16;
#pragma unroll
      for (int r = 0; r < 4; ++r)
        C[(size_t)(row0 + r) * N + col] = acc[mi][ni][r];
    }
}

// ---------------- flash attention (R15 + defer-max T13 + cvt_pk P-pack) ----------------
__global__ __launch_bounds__(256, 4) void attn_kernel(const u16* __restrict__ qkv,
                                                      const float* __restrict__ mask,
                                                      u16* __restrict__ AO) {
  __shared__ u16 Kt[2][64 * 64];   // [key][d]   swizzled, double-buffered
  __shared__ u16 Vt[64 * 64];      // [d][key]   swizzled (transposed)
  __shared__ u16 Pl[4][16 * 64];   // per-wave P swizzled (wave-private)

  const int tid  = threadIdx.x;
  const int w    = tid >> 6;
  const int lane = tid & 63;
  const int g    = lane >> 4;
  const int r16  = lane & 15;

  const int n  = blockIdx.x;
  const int x  = n & 7;
  const int s_ = n >> 3;
  const int h  = s_ & 15;
  const int t_ = ((s_ >> 4) << 3) + x;
  const int b  = t_ >> 5;
  const int qt = t_ & 31;

  const size_t tokbase = (size_t)b * SEQ;

  bf16x8 aq[2];
  {
    int qrow = qt * 64 + w * 16 + r16;
#pragma unroll
    for (int ko = 0; ko < 2; ++ko)
      aq[ko] = *reinterpret_cast<const bf16x8*>(
          qkv + ((tokbase + qrow) * 3 + 0) * HID + h * HD + ko * 32 + g * 8);
  }

  f32x4 o[4] = {};
  float mrow[4], lrow[4];
#pragma unroll
  for (int r = 0; r < 4; ++r) { mrow[r] = -3.0e38f; lrow[r] = 0.f; }

  const int srowK = lane >> 3;        // 0..7
  const int vkey  = tid >> 2;         // 0..63
  const int vd3   = tid & 3;

#define STAGE_K(buf, kb)                                                        \
  {                                                                             \
    _Pragma("unroll")                                                           \
    for (int c = 0; c < 2; ++c) {                                               \
      int seg = w * 2 + c;                                                      \
      int sK  = ((seg >> 1) + srowK) & 7;                                       \
      int srcc = (lane & 7) ^ sK;                                               \
      gld_lds16(qkv + ((tokbase + (kb) + seg * 8 + srowK) * 3 + 1) * HID +      \
                    h * HD + srcc * 8,                                          \
                &Kt[buf][seg * 512]);                                           \
    }                                                                           \
  }

  // ---- prologue: K tile 0 in flight ----
  STAGE_K(0, 0);

#pragma unroll 1
  for (int kb = 0; kb < SEQ; kb += 64) {
    const int cur = (kb >> 6) & 1;
    const int nxt = cur ^ 1;
    const bool more = (kb + 64) < SEQ;

    // ---- reg loads for THIS tile: mask + V ----
    float mpre[4][4];
#pragma unroll
    for (int r = 0; r < 4; ++r) {
      int q = qt * 64 + w * 16 + g * 4 + r;
      const float* mp = mask + ((size_t)b * SEQ + q) * SEQ + kb;
#pragma unroll
      for (int ni = 0; ni < 4; ++ni) mpre[r][ni] = mp[ni * 16 + r16];
    }
    const u16* vp = qkv + ((tokbase + kb + vkey) * 3 + 2) * HID + h * HD + vd3 * 16;
    u16x8 v0 = *reinterpret_cast<const u16x8*>(vp);
    u16x8 v1 = *reinterpret_cast<const u16x8*>(vp + 8);

    __syncthreads();   // A: prev-tile LDS reads done; drains vmcnt

    // ---- V -> LDS transposed, swizzled scalar writes ----
#pragma unroll
    for (int j = 0; j < 16; ++j) {
      u16 val = (j < 8) ? (u16)v0[j] : (u16)v1[j - 8];
      int row = vd3 * 16 + j;
      int sV  = (vd3 + (j & 7)) & 7;
      Vt[row * 64 + (((vkey >> 3) ^ sV) << 3) + (vkey & 7)] = val;
    }
    __syncthreads();   // B: Vt + Kt[cur] visible to all waves

    // ---- S = Q K^T on Kt[cur] ----
    f32x4 sf[4] = {};
    __builtin_amdgcn_s_setprio(1);
#pragma unroll
    for (int ko = 0; ko < 2; ++ko) {
      bf16x8 bk[4];
#pragma unroll
      for (int ni = 0; ni < 4; ++ni) {
        int row = ni * 16 + r16;
        int sK  = (ni + (r16 & 7)) & 7;
        bk[ni] = *reinterpret_cast<const bf16x8*>(
            &Kt[cur][row * 64 + (((ko * 4 + g) ^ sK) << 3)]);
      }
#pragma unroll
      for (int ni = 0; ni < 4; ++ni)
        sf[ni] = __builtin_amdgcn_mfma_f32_16x16x32_bf16(aq[ko], bk[ni], sf[ni], 0, 0, 0);
    }
    __builtin_amdgcn_s_setprio(0);

    // ---- online softmax: DPP rotate-reduce + defer-max (THR=8) ----
    float mx[4];
#pragma unroll
    for (int r = 0; r < 4; ++r) {
      float m_ = -3.0e38f;
#pragma unroll
      for (int ni = 0; ni < 4; ++ni) {
        float sv = sf[ni][r] * 0.125f + mpre[r][ni];
        sf[ni][r] = sv;
        m_ = fmaxf(m_, sv);
      }
      mx[r] = rowmax16(m_);
    }
    float need = 0.f;
#pragma unroll
    for (int r = 0; r < 4; ++r) need = fmaxf(need, mx[r] - mrow[r]);
    if (__any(need > 8.0f)) {
      // rescale path (rare after warm-up): update m, scale l and O
#pragma unroll
      for (int r = 0; r < 4; ++r) {
        float mnew  = fmaxf(mrow[r], mx[r]);
        float alpha = __expf(mrow[r] - mnew);
        mrow[r] = mnew;
        lrow[r] *= alpha;
#pragma unroll
        for (int di = 0; di < 4; ++di) o[di][r] *= alpha;
      }
    }
#pragma unroll
    for (int r = 0; r < 4; ++r) {
      float p0 = __expf(sf[0][r] - mrow[r]);
      float p1 = __expf(sf[1][r] - mrow[r]);
      float p2 = __expf(sf[2][r] - mrow[r]);
      float p3 = __expf(sf[3][r] - mrow[r]);
      float s  = rowsum16(p0 + p1 + p2 + p3);
      lrow[r] += s;
      // P-pack: 2 cvt_pk + 2 lshr instead of 4 bit-hack conversions
      unsigned pk01 = cvtpk(p0, p1);
      unsigned pk23 = cvtpk(p2, p3);
      int prow = g * 4 + r;
      int sP   = prow & 7;
      u16 pv[4] = { (u16)pk01, (u16)(pk01 >> 16), (u16)pk23, (u16)(pk23 >> 16) };
#pragma unroll
      for (int ni = 0; ni < 4; ++ni) {
        int chunk = ni * 2 + (r16 >> 3);
        Pl[w][prow * 64 + ((chunk ^ sP) << 3) + (r16 & 7)] = pv[ni];
      }
    }
    // no barrier: Pl[w] is wave-private; lgkmcnt orders write->read

    // ---- prefetch next K tile (zero-register) ----
    if (more) STAGE_K(nxt, kb + 64);

    // ---- O += P V ----
    __builtin_amdgcn_s_setprio(1);
#pragma unroll
    for (int kk = 0; kk < 2; ++kk) {
      bf16x8 pa, bv[4];
      pa = *reinterpret_cast<const bf16x8*>(
          &Pl[w][r16 * 64 + (((kk * 4 + g) ^ (r16 & 7)) << 3)]);
#pragma unroll
      for (int di = 0; di < 4; ++di) {
        int row = di * 16 + r16;
        int sV  = (di + (r16 & 7)) & 7;
        bv[di] = *reinterpret_cast<const bf16x8*>(
            &Vt[row * 64 + (((kk * 4 + g) ^ sV) << 3)]);
      }
#pragma unroll
      for (int di = 0; di < 4; ++di)
        o[di] = __builtin_amdgcn_mfma_f32_16x16x32_bf16(pa, bv[di], o[di], 0, 0, 0);
    }
    __builtin_amdgcn_s_setprio(0);
  }

  // finalize
#pragma unroll
  for (int di = 0; di < 4; ++di)
#pragma unroll
    for (int r = 0; r < 4; ++r) {
      int srow = qt * 64 + w * 16 + g * 4 + r;
      float val = o[di][r] / lrow[r];
      AO[(tokbase + srow) * HID + h * HD + di * 16 + r16] = f2bf(val);
    }
#undef STAGE_K
}

// ---------------- launcher ----------------
extern "C" void kernel_launch(void* const* d_in, const int* in_sizes, int n_in,
                              void* d_out, int out_size, void* d_ws, size_t ws_size,
                              hipStream_t stream) {
  (void)in_sizes; (void)n_in; (void)out_size; (void)ws_size;
  const float* hs   = (const float*)d_in[0];
  const float* mask = (const float*)d_in[1];
  const float* wqkv = (const float*)d_in[2];
  const float* wo   = (const float*)d_in[3];
  float* out = (float*)d_out;

  char* ws   = (char*)d_ws;
  u16* Xb    = (u16*)(ws);                        // 8 MiB
  u16* Wqkvb = (u16*)(ws + 8u  * 1024 * 1024);    // 6 MiB
  u16* Wob   = (u16*)(ws + 14u * 1024 * 1024);    // 2 MiB
  u16* QKVb  = (u16*)(ws + 16u * 1024 * 1024);    // 24 MiB
  u16* AOb   = (u16*)(ws + 40u * 1024 * 1024);    // 8 MiB

  cvt3_kernel<<<8192, 256, 0, stream>>>(hs, Xb, wqkv, Wqkvb, wo, Wob);

  gemm_bt<true><<<dim3(3072 / 128, 4096 / 128), 256, 0, stream>>>(Xb, Wqkvb, QKVb, NTOK, 3072, HID);
  attn_kernel  <<<1024, 256, 0, stream>>>(QKVb, mask, AOb);
  gemm_bt64    <<<dim3(1024 / 64, 4096 / 128), 256, 0, stream>>>(AOb, Wob, out, NTOK, 1024, HID);
}